// Round 8
// baseline (71.854 us; speedup 1.0000x reference)
//
#include <hip/hip_runtime.h>
#include <hip/hip_bf16.h>
#include <math.h>

#define NB      64      // batch
#define NNODES  1023    // 2*512-1
#define LC      20      // L*C = 5*4
#define DIN     512
#define NROWS   (NB * NNODES)   // 65472 = 1023 * 64 exactly
#define ET_PAD  404     // 400 + 4 pad

#define BM      64              // rows per gemm block (grid 1023 = 4 blocks/CU)
#define BK      64              // f32 k per chunk
#define NKC     (DIN / BK)      // 8 chunks
#define SCP     21              // epilogue scratch stride

typedef unsigned short u16;
typedef short bf16x8 __attribute__((ext_vector_type(8)));
typedef float f32x4  __attribute__((ext_vector_type(4)));

__device__ __forceinline__ u16 f2bf(float f) {   // RNE f32 -> bf16 bits
    unsigned x = __float_as_uint(f);
    return (u16)((x + 0x7FFFu + ((x >> 16) & 1u)) >> 16);
}

// ---------------------------------------------------------------------------
// prep: ET (exp(trans) reindexed) + B fragments in MFMA per-lane layout.
// Bfrag[fi*64 + lane] (uint4 = 8 bf16), fi = (ks*2+nf):
//   lane holds W[ks*32 + (lane>>4)*8 + j][nf*16 + (lane&15)], cols >= 20 zero.
// ---------------------------------------------------------------------------
__global__ __launch_bounds__(256) void prep_kernel(
    const float* __restrict__ trans, const float* __restrict__ W,
    float* __restrict__ ET, u16* __restrict__ Bfrag)
{
    int t = blockIdx.x * 256 + threadIdx.x;
    if (t < 8000) {
        int q   = t % 20;
        int rem = t / 20;
        int j   = rem % 20;
        int i   = rem / 20;
        int ll = i >> 2, cl = i & 3;
        int lr = j >> 2, cr = j & 3;
        int lp = q >> 2, cp = q & 3;
        int src = ((((lp * 5 + ll) * 5 + lr) * 4 + cp) * 4 + cl) * 4 + cr;
        ET[q * ET_PAD + i * 20 + j] = expf(trans[src]);
    }
    if (t < 2048) {
        int lane = t & 63, nf = (t >> 6) & 1, ks = t >> 7;
        int col = nf * 16 + (lane & 15);
        int kb  = ks * 32 + (lane >> 4) * 8;
        unsigned e[8];
        #pragma unroll
        for (int j = 0; j < 8; ++j)
            e[j] = (col < LC) ? (unsigned)f2bf(W[(kb + j) * LC + col]) : 0u;
        uint4 v;
        v.x = e[0] | (e[1] << 16); v.y = e[2] | (e[3] << 16);
        v.z = e[4] | (e[5] << 16); v.w = e[6] | (e[7] << 16);
        ((uint4*)Bfrag)[t] = v;
    }
}

// ---------------------------------------------------------------------------
// gemm via mfma_f32_16x16x32_bf16. BM=64, 4 waves; wave wv owns rows
// [wv*16, wv*16+16). A: f32 global -> RNE cvt -> swizzled bf16 LDS dbuf with
// 3-deep reg prefetch that SURVIVES barriers (raw s_barrier + lgkmcnt-only
// wait — no vmcnt drain). B: per-phase fragment loads from global (L2-hot),
// issued first in the phase so their vmcnt retirement keeps A-prefetch alive.
// ---------------------------------------------------------------------------
__global__ __launch_bounds__(256, 4) void gemm_kernel(
    const float* __restrict__ h, const u16* __restrict__ Bfrag,
    const float* __restrict__ bias, float* __restrict__ buf)
{
    __shared__ u16 AsU[2][BM][64];     // 16 KB
    const int t    = threadIdx.x;
    const int lane = t & 63;
    const int wv   = t >> 6;
    const size_t row0 = (size_t)blockIdx.x * BM;

    // staging geometry: thread covers rows srow+16i (i=0..3), f32-quad sk4
    const int srow = t >> 4;           // 0..15
    const int sk4  = t & 15;           // 0..15
    const int woff = (((sk4 >> 1) ^ (srow & 7)) << 3) + ((sk4 & 1) << 2); // u16
    const float* hp0 = h + (row0 + srow) * DIN + sk4 * 4;
    const float* hp1 = hp0 + 16 * DIN;
    const float* hp2 = hp0 + 32 * DIN;
    const float* hp3 = hp0 + 48 * DIN;

    f32x4 acc00 = {0.f,0.f,0.f,0.f}, acc01 = {0.f,0.f,0.f,0.f};
    float4 R0[4], R1[4], R2[4];

#define ISSUE(RB, CC) {                                                       \
    RB[0] = *(const float4*)(hp0 + (CC) * BK);                                \
    RB[1] = *(const float4*)(hp1 + (CC) * BK);                                \
    RB[2] = *(const float4*)(hp2 + (CC) * BK);                                \
    RB[3] = *(const float4*)(hp3 + (CC) * BK); }

#define CVTWRITE(RB, P) { u16* _b = &AsU[P][0][0] + woff; _Pragma("unroll")   \
    for (int i = 0; i < 4; ++i) {                                             \
        uint2 pk;                                                             \
        pk.x = (unsigned)f2bf(RB[i].x) | ((unsigned)f2bf(RB[i].y) << 16);     \
        pk.y = (unsigned)f2bf(RB[i].z) | ((unsigned)f2bf(RB[i].w) << 16);     \
        *(uint2*)(_b + (srow + 16 * i) * 64) = pk; } }

    // B-frag load first (oldest VMEM in phase), then compute
#define BCOMP(P, C) {                                                         \
    const uint4* _bp = (const uint4*)Bfrag + (size_t)(C) * 256 + lane;        \
    uint4 _f0 = _bp[0];   uint4 _f1 = _bp[64];                                \
    uint4 _f2 = _bp[128]; uint4 _f3 = _bp[192];                               \
    const u16* _ab = &AsU[P][0][0] + (wv * 16 + (lane & 15)) * 64;            \
    int _r0 = (((lane >> 4)    ) ^ (lane & 7)) << 3;                          \
    int _r1 = (((lane >> 4) + 4) ^ (lane & 7)) << 3;                          \
    bf16x8 _a0 = *(const bf16x8*)(_ab + _r0);                                 \
    bf16x8 _a1 = *(const bf16x8*)(_ab + _r1);                                 \
    acc00 = __builtin_amdgcn_mfma_f32_16x16x32_bf16(                          \
        _a0, __builtin_bit_cast(bf16x8, _f0), acc00, 0, 0, 0);                \
    acc01 = __builtin_amdgcn_mfma_f32_16x16x32_bf16(                          \
        _a0, __builtin_bit_cast(bf16x8, _f1), acc01, 0, 0, 0);                \
    acc00 = __builtin_amdgcn_mfma_f32_16x16x32_bf16(                          \
        _a1, __builtin_bit_cast(bf16x8, _f2), acc00, 0, 0, 0);                \
    acc01 = __builtin_amdgcn_mfma_f32_16x16x32_bf16(                          \
        _a1, __builtin_bit_cast(bf16x8, _f3), acc01, 0, 0, 0); }

    // raw barrier: drain LDS writes only — global prefetch stays in flight
#define BAR() { asm volatile("s_waitcnt lgkmcnt(0)" ::: "memory");            \
                __builtin_amdgcn_s_barrier(); }

    // prologue
    ISSUE(R0, 0); ISSUE(R1, 1); ISSUE(R2, 2);
    CVTWRITE(R0, 0);
    BAR();
    // 8 phases, fully static R-bank roles
    BCOMP(0, 0); ISSUE(R0, 3); CVTWRITE(R1, 1); BAR();
    BCOMP(1, 1); ISSUE(R1, 4); CVTWRITE(R2, 0); BAR();
    BCOMP(0, 2); ISSUE(R2, 5); CVTWRITE(R0, 1); BAR();
    BCOMP(1, 3); ISSUE(R0, 6); CVTWRITE(R1, 0); BAR();
    BCOMP(0, 4); ISSUE(R1, 7); CVTWRITE(R2, 1); BAR();
    BCOMP(1, 5);               CVTWRITE(R0, 0); BAR();
    BCOMP(0, 6);               CVTWRITE(R1, 1); BAR();
    BCOMP(1, 7);
#undef ISSUE
#undef CVTWRITE
#undef BCOMP
#undef BAR

    // epilogue: acc -> LDS scratch (over AsU[0], not read in phase 7) ->
    // coalesced float4 stores. 64 rows x 20 cols.
    float* sc = (float*)&AsU[0][0][0];   // 64*21*4 = 5376 B < 8 KB
    #pragma unroll
    for (int nf = 0; nf < 2; ++nf) {
        f32x4 a = nf ? acc01 : acc00;
        int col = nf * 16 + (lane & 15);
        if (col < LC) {
            float bv = bias[col];
            #pragma unroll
            for (int p = 0; p < 4; ++p) {
                int rl = wv * 16 + (lane >> 4) * 4 + p;
                sc[rl * SCP + col] = a[p] + bv;
            }
        }
    }
    __syncthreads();
    {
        float4* dst = (float4*)(buf + row0 * LC);   // 320 float4 per block
        int f0 = t * 4;
        float4 o;
        o.x = sc[((f0 + 0) / 20) * SCP + (f0 + 0) % 20];
        o.y = sc[((f0 + 1) / 20) * SCP + (f0 + 1) % 20];
        o.z = sc[((f0 + 2) / 20) * SCP + (f0 + 2) % 20];
        o.w = sc[((f0 + 3) / 20) * SCP + (f0 + 3) % 20];
        dst[t] = o;
        if (t < 64) {
            int p = 256 + t, g0 = p * 4;
            float4 o2;
            o2.x = sc[((g0 + 0) / 20) * SCP + (g0 + 0) % 20];
            o2.y = sc[((g0 + 1) / 20) * SCP + (g0 + 1) % 20];
            o2.z = sc[((g0 + 2) / 20) * SCP + (g0 + 2) % 20];
            o2.w = sc[((g0 + 3) / 20) * SCP + (g0 + 3) % 20];
            dst[p] = o2;
        }
    }
}

// ---------------------------------------------------------------------------
// level body (shared by level_kernel and tail_kernel)
// ---------------------------------------------------------------------------
__device__ __forceinline__ void level_body(
    float* __restrict__ buf, const float* __restrict__ et,
    float* __restrict__ out, int bi, int node, int q)
{
    size_t pbase = ((size_t)bi * NNODES + node) * LC;
    size_t lbase = ((size_t)bi * NNODES + 2 * node + 1) * LC;

    float l[LC], r[LC];
    const float4* l4 = (const float4*)(buf + lbase);
    const float4* r4 = (const float4*)(buf + lbase + LC);
    #pragma unroll
    for (int v = 0; v < 5; ++v) {
        float4 lv = l4[v], rv = r4[v];
        l[4*v+0] = lv.x; l[4*v+1] = lv.y; l[4*v+2] = lv.z; l[4*v+3] = lv.w;
        r[4*v+0] = rv.x; r[4*v+1] = rv.y; r[4*v+2] = rv.z; r[4*v+3] = rv.w;
    }
    float maxl = l[0], maxr = r[0];
    #pragma unroll
    for (int i = 1; i < LC; ++i) {
        maxl = fmaxf(maxl, l[i]);
        maxr = fmaxf(maxr, r[i]);
    }
    float el[LC], er[LC];
    #pragma unroll
    for (int i = 0; i < LC; ++i) {
        el[i] = __expf(l[i] - maxl);
        er[i] = __expf(r[i] - maxr);
    }

    const float4* etq = (const float4*)(et + q * ET_PAD);
    float s = 0.f;
    #pragma unroll
    for (int i = 0; i < LC; ++i) {
        float4 e0 = etq[i*5+0], e1 = etq[i*5+1], e2 = etq[i*5+2],
               e3 = etq[i*5+3], e4 = etq[i*5+4];
        float d0 = 0.f, d1 = 0.f;
        d0 = fmaf(e0.x, er[0],  d0); d1 = fmaf(e0.y, er[1],  d1);
        d0 = fmaf(e0.z, er[2],  d0); d1 = fmaf(e0.w, er[3],  d1);
        d0 = fmaf(e1.x, er[4],  d0); d1 = fmaf(e1.y, er[5],  d1);
        d0 = fmaf(e1.z, er[6],  d0); d1 = fmaf(e1.w, er[7],  d1);
        d0 = fmaf(e2.x, er[8],  d0); d1 = fmaf(e2.y, er[9],  d1);
        d0 = fmaf(e2.z, er[10], d0); d1 = fmaf(e2.w, er[11], d1);
        d0 = fmaf(e3.x, er[12], d0); d1 = fmaf(e3.y, er[13], d1);
        d0 = fmaf(e3.z, er[14], d0); d1 = fmaf(e3.w, er[15], d1);
        d0 = fmaf(e4.x, er[16], d0); d1 = fmaf(e4.y, er[17], d1);
        d0 = fmaf(e4.z, er[18], d0); d1 = fmaf(e4.w, er[19], d1);
        s = fmaf(el[i], d0 + d1, s);
    }

    float val = buf[pbase + q] + maxl + maxr + __logf(s);
    buf[pbase + q] = val;
    if (out) out[(size_t)bi * LC + q] = val;
}

// ---------------------------------------------------------------------------
// level: one launch per level for d = 8, 7
// ---------------------------------------------------------------------------
__global__ __launch_bounds__(256) void level_kernel(
    float* __restrict__ buf, const float* __restrict__ ETg,
    int start, int count)
{
    __shared__ float et[LC * ET_PAD];
    for (int idx = threadIdx.x; idx < LC * ET_PAD / 4; idx += 256)
        ((float4*)et)[idx] = ((const float4*)ETg)[idx];
    __syncthreads();

    int t  = blockIdx.x * 256 + threadIdx.x;
    int pj = t / LC;
    int q  = t - pj * LC;
    if (pj >= NB * count) return;
    int bi   = pj / count;
    int node = start + (pj - bi * count);
    level_body(buf, et, nullptr, bi, node, q);
}

// ---------------------------------------------------------------------------
// tail: levels d = 6..0 fused, one block per batch element
// ---------------------------------------------------------------------------
__global__ __launch_bounds__(640) void tail_kernel(
    float* __restrict__ buf, const float* __restrict__ ETg,
    float* __restrict__ out)
{
    __shared__ float et[LC * ET_PAD];
    for (int idx = threadIdx.x; idx < LC * ET_PAD / 4; idx += 640)
        ((float4*)et)[idx] = ((const float4*)ETg)[idx];
    __syncthreads();

    const int bi = blockIdx.x;
    for (int d = 6; d >= 0; --d) {
        int count = 1 << d;
        int start = count - 1;
        int total = count * LC;
        for (int base = 0; base < total; base += 640) {
            int idx = base + (int)threadIdx.x;
            if (idx < total) {
                int node = start + idx / LC;
                int q    = idx % LC;
                level_body(buf, et, (d == 0) ? out : nullptr, bi, node, q);
            }
        }
        __syncthreads();
    }
}

// ---------------------------------------------------------------------------
extern "C" void kernel_launch(void* const* d_in, const int* in_sizes, int n_in,
                              void* d_out, int out_size, void* d_ws, size_t ws_size,
                              hipStream_t stream)
{
    const float* h     = (const float*)d_in[0];
    const float* W     = (const float*)d_in[1];
    const float* bias  = (const float*)d_in[2];
    const float* trans = (const float*)d_in[3];

    char* ws = (char*)d_ws;
    float* ET    = (float*)(ws);                     // 32320 B (pad to 32768)
    u16*   Bfrag = (u16*)(ws + 32768);               // 32768 B
    float* buf   = (float*)(ws + 65536);             // 65472*20*4 B

    // 1. precompute exp(trans) reindexed + B fragments
    prep_kernel<<<32, 256, 0, stream>>>(trans, W, ET, Bfrag);

    // 2. sw = h@W + b  (MFMA bf16, 1023 blocks = 4 per CU)
    gemm_kernel<<<NROWS / BM, 256, 0, stream>>>(h, Bfrag, bias, buf);

    // 3. inside pass: d=8,7 separate, d=6..0 fused
    for (int d = 8; d >= 7; --d) {
        int count = 1 << d;
        int start = count - 1;
        int T = NB * count * LC;
        level_kernel<<<(T + 255) / 256, 256, 0, stream>>>(buf, ET, start, count);
    }
    tail_kernel<<<NB, 640, 0, stream>>>(buf, ET, (float*)d_out);
}

// Round 9
// 71.722 us; speedup vs baseline: 1.0018x; 1.0018x over previous
//
#include <hip/hip_runtime.h>
#include <hip/hip_bf16.h>
#include <math.h>

#define NB      64      // batch
#define NNODES  1023    // 2*512-1
#define LC      20      // L*C = 5*4
#define DIN     512
#define NROWS   (NB * NNODES)   // 65472 = 1023 * 64 exactly
#define ET_PAD  404     // 400 + 4 pad

#define BM      64              // rows per gemm block (grid 1023 = 4 blocks/CU)
#define BK      64              // f32 k per chunk
#define NKC     (DIN / BK)      // 8 chunks
#define SCP     21              // epilogue scratch stride

typedef unsigned short u16;
typedef short bf16x8 __attribute__((ext_vector_type(8)));
typedef float f32x4  __attribute__((ext_vector_type(4)));

__device__ __forceinline__ u16 f2bf(float f) {   // RNE f32 -> bf16 bits
    unsigned x = __float_as_uint(f);
    return (u16)((x + 0x7FFFu + ((x >> 16) & 1u)) >> 16);
}

// ---------------------------------------------------------------------------
// prep: ET (exp(trans) reindexed) + B fragments, compact layout (1280 uint4):
//  [0,1024):  nf=0 full:  idx = ks*64 + lane -> W[ks*32+(lane>>4)*8+j][lane&15]
//  [1024,1280): nf=1 compact: idx = 1024 + ks*16 + g*4 + c
//                             -> W[ks*32+g*8+j][16+c]   (c = 0..3)
// ---------------------------------------------------------------------------
__global__ __launch_bounds__(256) void prep_kernel(
    const float* __restrict__ trans, const float* __restrict__ W,
    float* __restrict__ ET, u16* __restrict__ Bfrag)
{
    int t = blockIdx.x * 256 + threadIdx.x;
    if (t < 8000) {
        int q   = t % 20;
        int rem = t / 20;
        int j   = rem % 20;
        int i   = rem / 20;
        int ll = i >> 2, cl = i & 3;
        int lr = j >> 2, cr = j & 3;
        int lp = q >> 2, cp = q & 3;
        int src = ((((lp * 5 + ll) * 5 + lr) * 4 + cp) * 4 + cl) * 4 + cr;
        ET[q * ET_PAD + i * 20 + j] = expf(trans[src]);
    }
    if (t < 1280) {
        int col, kb;
        if (t < 1024) {
            int lane = t & 63, ks = t >> 6;
            col = lane & 15;
            kb  = ks * 32 + ((lane >> 4) & 3) * 8;
        } else {
            int idx = t - 1024;
            int ks = idx >> 4, g = (idx >> 2) & 3, c = idx & 3;
            col = 16 + c;
            kb  = ks * 32 + g * 8;
        }
        unsigned e[8];
        #pragma unroll
        for (int j = 0; j < 8; ++j)
            e[j] = (unsigned)f2bf(W[(kb + j) * LC + col]);
        uint4 v;
        v.x = e[0] | (e[1] << 16); v.y = e[2] | (e[3] << 16);
        v.z = e[4] | (e[5] << 16); v.w = e[6] | (e[7] << 16);
        ((uint4*)Bfrag)[t] = v;
    }
}

// ---------------------------------------------------------------------------
// gemm via mfma_f32_16x16x32_bf16. BM=64, 4 waves; wave wv owns rows
// [wv*16, wv*16+16).
// A: f32 global -> RNE cvt -> swizzled bf16 LDS dbuf, 3-deep reg prefetch.
// B: in LDS (copied once, compact 20 KB) read via ds_read -> lgkmcnt only,
//    so the vmcnt FIFO holds NOTHING but A-prefetch, retired strictly
//    oldest-first by CVTWRITE 2 phases later. Barriers are lgkm-only —
//    the A pipeline NEVER drains.
// ---------------------------------------------------------------------------
__global__ __launch_bounds__(256, 4) void gemm_kernel(
    const float* __restrict__ h, const u16* __restrict__ Bfrag,
    const float* __restrict__ bias, float* __restrict__ buf)
{
    __shared__ u16  AsU[2][BM][64];    // 16 KB A tiles (swizzled bf16)
    __shared__ uint4 Bs[1280];         // 20 KB B fragments
    const int t    = threadIdx.x;
    const int lane = t & 63;
    const int wv   = t >> 6;
    const size_t row0 = (size_t)blockIdx.x * BM;

    // B fragments -> LDS (1280 uint4, 5 per thread, coalesced)
    #pragma unroll
    for (int i = 0; i < 5; ++i)
        Bs[t + 256 * i] = ((const uint4*)Bfrag)[t + 256 * i];

    // staging geometry: thread covers rows srow+16i (i=0..3), f32-quad sk4
    const int srow = t >> 4;           // 0..15
    const int sk4  = t & 15;           // 0..15
    const int woff = (((sk4 >> 1) ^ (srow & 7)) << 3) + ((sk4 & 1) << 2); // u16
    const float* hp0 = h + (row0 + srow) * DIN + sk4 * 4;
    const float* hp1 = hp0 + 16 * DIN;
    const float* hp2 = hp0 + 32 * DIN;
    const float* hp3 = hp0 + 48 * DIN;

    f32x4 acc00 = {0.f,0.f,0.f,0.f}, acc01 = {0.f,0.f,0.f,0.f};
    float4 R0[4], R1[4], R2[4];
    const uint4 z4 = make_uint4(0u, 0u, 0u, 0u);

#define ISSUE(RB, CC) {                                                       \
    RB[0] = *(const float4*)(hp0 + (CC) * BK);                                \
    RB[1] = *(const float4*)(hp1 + (CC) * BK);                                \
    RB[2] = *(const float4*)(hp2 + (CC) * BK);                                \
    RB[3] = *(const float4*)(hp3 + (CC) * BK); }

#define CVTWRITE(RB, P) { u16* _b = &AsU[P][0][0] + woff; _Pragma("unroll")   \
    for (int i = 0; i < 4; ++i) {                                             \
        uint2 pk;                                                             \
        pk.x = (unsigned)f2bf(RB[i].x) | ((unsigned)f2bf(RB[i].y) << 16);     \
        pk.y = (unsigned)f2bf(RB[i].z) | ((unsigned)f2bf(RB[i].w) << 16);     \
        *(uint2*)(_b + (srow + 16 * i) * 64) = pk; } }

    // all operand reads are DS ops (lgkmcnt); MFMA never touches vmcnt
#define BCOMP(P, C) {                                                         \
    const u16* _ab = &AsU[P][0][0] + (wv * 16 + (lane & 15)) * 64;            \
    int _r0 = (((lane >> 4)    ) ^ (lane & 7)) << 3;                          \
    int _r1 = (((lane >> 4) + 4) ^ (lane & 7)) << 3;                          \
    bf16x8 _a0 = *(const bf16x8*)(_ab + _r0);                                 \
    bf16x8 _a1 = *(const bf16x8*)(_ab + _r1);                                 \
    uint4 _b00 = Bs[(2 * (C)    ) * 64 + lane];                               \
    uint4 _b02 = Bs[(2 * (C) + 1) * 64 + lane];                               \
    uint4 _b10 = Bs[1024 + (2 * (C)    ) * 16 + ((lane >> 4) << 2) + (lane & 3)]; \
    uint4 _b12 = Bs[1024 + (2 * (C) + 1) * 16 + ((lane >> 4) << 2) + (lane & 3)]; \
    if ((lane & 15) >= 4) { _b10 = z4; _b12 = z4; }                           \
    acc00 = __builtin_amdgcn_mfma_f32_16x16x32_bf16(                          \
        _a0, __builtin_bit_cast(bf16x8, _b00), acc00, 0, 0, 0);               \
    acc01 = __builtin_amdgcn_mfma_f32_16x16x32_bf16(                          \
        _a0, __builtin_bit_cast(bf16x8, _b10), acc01, 0, 0, 0);               \
    acc00 = __builtin_amdgcn_mfma_f32_16x16x32_bf16(                          \
        _a1, __builtin_bit_cast(bf16x8, _b02), acc00, 0, 0, 0);               \
    acc01 = __builtin_amdgcn_mfma_f32_16x16x32_bf16(                          \
        _a1, __builtin_bit_cast(bf16x8, _b12), acc01, 0, 0, 0); }

    // raw barrier: drain LDS ops only — global A-prefetch stays in flight
#define BAR() { asm volatile("s_waitcnt lgkmcnt(0)" ::: "memory");            \
                __builtin_amdgcn_s_barrier(); }

    // prologue: B-copy above; 3 A-chunks issued, chunk0 staged
    ISSUE(R0, 0); ISSUE(R1, 1); ISSUE(R2, 2);
    CVTWRITE(R0, 0);
    BAR();
    // 8 phases, fully static R-bank roles
    BCOMP(0, 0); ISSUE(R0, 3); CVTWRITE(R1, 1); BAR();
    BCOMP(1, 1); ISSUE(R1, 4); CVTWRITE(R2, 0); BAR();
    BCOMP(0, 2); ISSUE(R2, 5); CVTWRITE(R0, 1); BAR();
    BCOMP(1, 3); ISSUE(R0, 6); CVTWRITE(R1, 0); BAR();
    BCOMP(0, 4); ISSUE(R1, 7); CVTWRITE(R2, 1); BAR();
    BCOMP(1, 5);               CVTWRITE(R0, 0); BAR();
    BCOMP(0, 6);               CVTWRITE(R1, 1); BAR();
    BCOMP(1, 7);
#undef ISSUE
#undef CVTWRITE
#undef BCOMP
#undef BAR

    // epilogue: acc -> LDS scratch (over AsU[0], phase 7 read AsU[1]) ->
    // coalesced float4 stores. 64 rows x 20 cols.
    float* sc = (float*)&AsU[0][0][0];   // 64*21*4 = 5376 B < 8 KB
    #pragma unroll
    for (int nf = 0; nf < 2; ++nf) {
        f32x4 a = nf ? acc01 : acc00;
        int col = nf * 16 + (lane & 15);
        if (col < LC) {
            float bv = bias[col];
            #pragma unroll
            for (int p = 0; p < 4; ++p) {
                int rl = wv * 16 + (lane >> 4) * 4 + p;
                sc[rl * SCP + col] = a[p] + bv;
            }
        }
    }
    __syncthreads();
    {
        float4* dst = (float4*)(buf + row0 * LC);   // 320 float4 per block
        int f0 = t * 4;
        float4 o;
        o.x = sc[((f0 + 0) / 20) * SCP + (f0 + 0) % 20];
        o.y = sc[((f0 + 1) / 20) * SCP + (f0 + 1) % 20];
        o.z = sc[((f0 + 2) / 20) * SCP + (f0 + 2) % 20];
        o.w = sc[((f0 + 3) / 20) * SCP + (f0 + 3) % 20];
        dst[t] = o;
        if (t < 64) {
            int p = 256 + t, g0 = p * 4;
            float4 o2;
            o2.x = sc[((g0 + 0) / 20) * SCP + (g0 + 0) % 20];
            o2.y = sc[((g0 + 1) / 20) * SCP + (g0 + 1) % 20];
            o2.z = sc[((g0 + 2) / 20) * SCP + (g0 + 2) % 20];
            o2.w = sc[((g0 + 3) / 20) * SCP + (g0 + 3) % 20];
            dst[p] = o2;
        }
    }
}

// ---------------------------------------------------------------------------
// level body (shared by level_kernel and tail_kernel)
// ---------------------------------------------------------------------------
__device__ __forceinline__ void level_body(
    float* __restrict__ buf, const float* __restrict__ et,
    float* __restrict__ out, int bi, int node, int q)
{
    size_t pbase = ((size_t)bi * NNODES + node) * LC;
    size_t lbase = ((size_t)bi * NNODES + 2 * node + 1) * LC;

    float l[LC], r[LC];
    const float4* l4 = (const float4*)(buf + lbase);
    const float4* r4 = (const float4*)(buf + lbase + LC);
    #pragma unroll
    for (int v = 0; v < 5; ++v) {
        float4 lv = l4[v], rv = r4[v];
        l[4*v+0] = lv.x; l[4*v+1] = lv.y; l[4*v+2] = lv.z; l[4*v+3] = lv.w;
        r[4*v+0] = rv.x; r[4*v+1] = rv.y; r[4*v+2] = rv.z; r[4*v+3] = rv.w;
    }
    float maxl = l[0], maxr = r[0];
    #pragma unroll
    for (int i = 1; i < LC; ++i) {
        maxl = fmaxf(maxl, l[i]);
        maxr = fmaxf(maxr, r[i]);
    }
    float el[LC], er[LC];
    #pragma unroll
    for (int i = 0; i < LC; ++i) {
        el[i] = __expf(l[i] - maxl);
        er[i] = __expf(r[i] - maxr);
    }

    const float4* etq = (const float4*)(et + q * ET_PAD);
    float s = 0.f;
    #pragma unroll
    for (int i = 0; i < LC; ++i) {
        float4 e0 = etq[i*5+0], e1 = etq[i*5+1], e2 = etq[i*5+2],
               e3 = etq[i*5+3], e4 = etq[i*5+4];
        float d0 = 0.f, d1 = 0.f;
        d0 = fmaf(e0.x, er[0],  d0); d1 = fmaf(e0.y, er[1],  d1);
        d0 = fmaf(e0.z, er[2],  d0); d1 = fmaf(e0.w, er[3],  d1);
        d0 = fmaf(e1.x, er[4],  d0); d1 = fmaf(e1.y, er[5],  d1);
        d0 = fmaf(e1.z, er[6],  d0); d1 = fmaf(e1.w, er[7],  d1);
        d0 = fmaf(e2.x, er[8],  d0); d1 = fmaf(e2.y, er[9],  d1);
        d0 = fmaf(e2.z, er[10], d0); d1 = fmaf(e2.w, er[11], d1);
        d0 = fmaf(e3.x, er[12], d0); d1 = fmaf(e3.y, er[13], d1);
        d0 = fmaf(e3.z, er[14], d0); d1 = fmaf(e3.w, er[15], d1);
        d0 = fmaf(e4.x, er[16], d0); d1 = fmaf(e4.y, er[17], d1);
        d0 = fmaf(e4.z, er[18], d0); d1 = fmaf(e4.w, er[19], d1);
        s = fmaf(el[i], d0 + d1, s);
    }

    float val = buf[pbase + q] + maxl + maxr + __logf(s);
    buf[pbase + q] = val;
    if (out) out[(size_t)bi * LC + q] = val;
}

// ---------------------------------------------------------------------------
// level: one launch per level for d = 8, 7
// ---------------------------------------------------------------------------
__global__ __launch_bounds__(256) void level_kernel(
    float* __restrict__ buf, const float* __restrict__ ETg,
    int start, int count)
{
    __shared__ float et[LC * ET_PAD];
    for (int idx = threadIdx.x; idx < LC * ET_PAD / 4; idx += 256)
        ((float4*)et)[idx] = ((const float4*)ETg)[idx];
    __syncthreads();

    int t  = blockIdx.x * 256 + threadIdx.x;
    int pj = t / LC;
    int q  = t - pj * LC;
    if (pj >= NB * count) return;
    int bi   = pj / count;
    int node = start + (pj - bi * count);
    level_body(buf, et, nullptr, bi, node, q);
}

// ---------------------------------------------------------------------------
// tail: levels d = 6..0 fused, one block per batch element
// ---------------------------------------------------------------------------
__global__ __launch_bounds__(640) void tail_kernel(
    float* __restrict__ buf, const float* __restrict__ ETg,
    float* __restrict__ out)
{
    __shared__ float et[LC * ET_PAD];
    for (int idx = threadIdx.x; idx < LC * ET_PAD / 4; idx += 640)
        ((float4*)et)[idx] = ((const float4*)ETg)[idx];
    __syncthreads();

    const int bi = blockIdx.x;
    for (int d = 6; d >= 0; --d) {
        int count = 1 << d;
        int start = count - 1;
        int total = count * LC;
        for (int base = 0; base < total; base += 640) {
            int idx = base + (int)threadIdx.x;
            if (idx < total) {
                int node = start + idx / LC;
                int q    = idx % LC;
                level_body(buf, et, (d == 0) ? out : nullptr, bi, node, q);
            }
        }
        __syncthreads();
    }
}

// ---------------------------------------------------------------------------
extern "C" void kernel_launch(void* const* d_in, const int* in_sizes, int n_in,
                              void* d_out, int out_size, void* d_ws, size_t ws_size,
                              hipStream_t stream)
{
    const float* h     = (const float*)d_in[0];
    const float* W     = (const float*)d_in[1];
    const float* bias  = (const float*)d_in[2];
    const float* trans = (const float*)d_in[3];

    char* ws = (char*)d_ws;
    float* ET    = (float*)(ws);                     // 32320 B (pad to 32768)
    u16*   Bfrag = (u16*)(ws + 32768);               // 20480 B (pad to 24576)
    float* buf   = (float*)(ws + 32768 + 24576);     // 65472*20*4 B

    // 1. precompute exp(trans) reindexed + compact B fragments
    prep_kernel<<<32, 256, 0, stream>>>(trans, W, ET, Bfrag);

    // 2. sw = h@W + b  (MFMA bf16, 1023 blocks = 4 per CU, all co-resident)
    gemm_kernel<<<NROWS / BM, 256, 0, stream>>>(h, Bfrag, bias, buf);

    // 3. inside pass: d=8,7 separate, d=6..0 fused
    for (int d = 8; d >= 7; --d) {
        int count = 1 << d;
        int start = count - 1;
        int T = NB * count * LC;
        level_kernel<<<(T + 255) / 256, 256, 0, stream>>>(buf, ET, start, count);
    }
    tail_kernel<<<NB, 640, 0, stream>>>(buf, ET, (float*)d_out);
}